// Round 3
// baseline (458.059 us; speedup 1.0000x reference)
//
#include <hip/hip_runtime.h>
#include <hip/hip_bf16.h>
#include <stddef.h>

// ---------------------------------------------------------------------------
// WaveNet residual block, fused.  B=8 T=16384 C=128 F=256 K=3 dil=8
// K-dim layout for GEMM1 (total 544 = 17 * 32):
//   [0,384)   conv: kk = k*128 + c   -> x[t-16+8k][c]
//   [384,480) lc (80 data + 16 zero pad)
//   [480,544) gc (64)
// Weights stored WN-normalized, bf16, MFMA-fragment order:
//   frag[kstep][ntile][lane][8], value = W[kstep*32 + (lane>>4)*8 + j][ntile*16 + (lane&15)]
// ---------------------------------------------------------------------------

typedef __attribute__((ext_vector_type(4))) float  f32x4;
typedef __attribute__((ext_vector_type(8))) short  sh8;
typedef __attribute__((ext_vector_type(4))) short  sh4;

#define T_LEN   16384
#define OUT_HALF 16777216   // 8*16384*128

static __device__ __forceinline__ unsigned short f2bf(float f) {
    unsigned u = __builtin_bit_cast(unsigned, f);
    unsigned r = u + 0x7FFFu + ((u >> 16) & 1u);
    return (unsigned short)(r >> 16);
}

// ------------------------------ weight prep --------------------------------
__global__ void wp_scales(const float* __restrict__ conv_k, const float* __restrict__ conv_g,
                          const float* __restrict__ lc_k,   const float* __restrict__ lc_g,
                          const float* __restrict__ gc_k,   const float* __restrict__ gc_g,
                          const float* __restrict__ skip_k, const float* __restrict__ skip_g,
                          const float* __restrict__ out_k,  const float* __restrict__ out_g,
                          float* __restrict__ scales) {
    int bid = blockIdx.x, tid = threadIdx.x;
    if (bid == 0) {            // conv: 256 outputs, 384 K
        float ss = 0.f;
        for (int i = 0; i < 384; ++i) { float v = conv_k[i*256 + tid]; ss += v*v; }
        scales[tid] = conv_g[tid] * rsqrtf(fmaxf(ss, 1e-12f));
    } else if (bid == 1) {     // lc: 256 outputs, 80 K
        float ss = 0.f;
        for (int i = 0; i < 80; ++i) { float v = lc_k[i*256 + tid]; ss += v*v; }
        scales[256 + tid] = lc_g[tid] * rsqrtf(fmaxf(ss, 1e-12f));
    } else if (bid == 2) {     // gc: 256 outputs, 64 K
        float ss = 0.f;
        for (int i = 0; i < 64; ++i) { float v = gc_k[i*256 + tid]; ss += v*v; }
        scales[512 + tid] = gc_g[tid] * rsqrtf(fmaxf(ss, 1e-12f));
    } else if (bid == 3) {     // skip: 128 outputs, 128 K
        if (tid < 128) {
            float ss = 0.f;
            for (int i = 0; i < 128; ++i) { float v = skip_k[i*128 + tid]; ss += v*v; }
            scales[768 + tid] = skip_g[tid] * rsqrtf(fmaxf(ss, 1e-12f));
        }
    } else {                   // out: 128 outputs, 128 K
        if (tid < 128) {
            float ss = 0.f;
            for (int i = 0; i < 128; ++i) { float v = out_k[i*128 + tid]; ss += v*v; }
            scales[896 + tid] = out_g[tid] * rsqrtf(fmaxf(ss, 1e-12f));
        }
    }
}

__global__ void wp_frags(const float* __restrict__ conv_k, const float* __restrict__ lc_k,
                         const float* __restrict__ gc_k,   const float* __restrict__ skip_k,
                         const float* __restrict__ out_k,  const float* __restrict__ scales,
                         unsigned short* __restrict__ w1f,
                         unsigned short* __restrict__ wsf,
                         unsigned short* __restrict__ wof) {
    int idx = blockIdx.x * 256 + threadIdx.x;
    if (idx < 139264) {                       // W1: [17][16][64][8]
        int j = idx & 7, lane = (idx >> 3) & 63, ntile = (idx >> 9) & 15, ks = idx >> 13;
        int kk = ks*32 + (lane >> 4)*8 + j;
        int f  = ntile*16 + (lane & 15);
        float v;
        if      (kk < 384) v = conv_k[kk*256 + f]        * scales[f];
        else if (kk < 464) v = lc_k[(kk-384)*256 + f]    * scales[256 + f];
        else if (kk < 480) v = 0.f;
        else               v = gc_k[(kk-480)*256 + f]    * scales[512 + f];
        w1f[idx] = f2bf(v);
    } else if (idx < 155648) {                // Wskip: [4][8][64][8]
        int e = idx - 139264;
        int j = e & 7, lane = (e >> 3) & 63, ntile = (e >> 9) & 7, ks = e >> 12;
        int kk = ks*32 + (lane >> 4)*8 + j;
        int s  = ntile*16 + (lane & 15);
        wsf[e] = f2bf(skip_k[kk*128 + s] * scales[768 + s]);
    } else if (idx < 172032) {                // Wout: [4][8][64][8]
        int e = idx - 155648;
        int j = e & 7, lane = (e >> 3) & 63, ntile = (e >> 9) & 7, ks = e >> 12;
        int kk = ks*32 + (lane >> 4)*8 + j;
        int c  = ntile*16 + (lane & 15);
        wof[e] = f2bf(out_k[kk*128 + c] * scales[896 + c]);
    }
}

// ------------------------------ main kernel --------------------------------
// LDS layout (bytes), all XOR-swizzled with ((row&7)<<4); every region has a
// row stride that is a multiple of 128 B, so the XOR is bijective within a row.
//   X_OFF : x tile  [80][128] bf16, row stride 256 B   (rows t0-16 .. t0+63)
//   LC_OFF: lc tile [64][128] bf16, row stride 256 B   (cols 80..127 zero)
//   GC_OFF: gc tile [64][64]  bf16, row stride 128 B
//   G_OFF : gated   [64][128] bf16, row stride 256 B -- ALIASES X (after barrier)
#define X_OFF  0
#define G_OFF  0
#define LC_OFF 20480
#define GC_OFF 36864
#define SMEM_SZ 45056

__global__ __launch_bounds__(256, 3)
void wn_main(const float* __restrict__ x, const float* __restrict__ lc,
             const float* __restrict__ gc,
             const float* __restrict__ conv_bias, const float* __restrict__ skip_bias,
             const float* __restrict__ out_bias,
             const unsigned short* __restrict__ w1f,
             const unsigned short* __restrict__ wsf,
             const unsigned short* __restrict__ wof,
             float* __restrict__ out) {
    __shared__ __align__(16) char smem[SMEM_SZ];

    const int tid  = threadIdx.x;
    const int wave = tid >> 6, lane = tid & 63;
    const int bid  = blockIdx.x;
    const int b    = bid >> 8;          // 256 blocks per batch (T/64)
    const int t0   = (bid & 255) << 6;  // 64 timesteps per block

    const float* xb  = x  + (size_t)b * T_LEN * 128;
    const float* lcb = lc + (size_t)b * T_LEN * 80;
    const float* gcb = gc + (size_t)b * T_LEN * 64;

    // ---- stage x tile: 80 rows x 128 ch = 2560 float4, 10 iters ----
    #pragma unroll
    for (int it = 0; it < 10; ++it) {
        int idx = it*256 + tid;
        int r = idx >> 5, cg = idx & 31;
        int t = t0 - 16 + r;
        f32x4 v = {0.f, 0.f, 0.f, 0.f};
        if (t >= 0) v = *(const f32x4*)(xb + (size_t)t*128 + cg*4);
        sh4 h; h[0]=(short)f2bf(v[0]); h[1]=(short)f2bf(v[1]); h[2]=(short)f2bf(v[2]); h[3]=(short)f2bf(v[3]);
        int addr = X_OFF + ((r*256 + cg*8) ^ ((r & 7) << 4));
        *(sh4*)(smem + addr) = h;
    }
    // ---- stage lc tile: 64 rows x 80 ch = 1280 float4, 5 iters ----
    #pragma unroll
    for (int it = 0; it < 5; ++it) {
        int idx = it*256 + tid;
        int r = idx / 20, cg = idx - r*20;
        f32x4 v = *(const f32x4*)(lcb + (size_t)(t0 + r)*80 + cg*4);
        sh4 h; h[0]=(short)f2bf(v[0]); h[1]=(short)f2bf(v[1]); h[2]=(short)f2bf(v[2]); h[3]=(short)f2bf(v[3]);
        int addr = LC_OFF + ((r*256 + cg*8) ^ ((r & 7) << 4));
        *(sh4*)(smem + addr) = h;
    }
    // lc zero pad cols 80..127: 64 rows x 12 groups of 8B = 768
    #pragma unroll
    for (int it = 0; it < 3; ++it) {
        int idx = it*256 + tid;
        int r = idx / 12, cg2 = idx - r*12;
        sh4 z = {0,0,0,0};
        int addr = LC_OFF + ((r*256 + 160 + cg2*8) ^ ((r & 7) << 4));
        *(sh4*)(smem + addr) = z;
    }
    // ---- stage gc tile: 64 rows x 64 ch = 1024 float4, 4 iters ----
    #pragma unroll
    for (int it = 0; it < 4; ++it) {
        int idx = it*256 + tid;
        int r = idx >> 4, cg = idx & 15;
        f32x4 v = *(const f32x4*)(gcb + (size_t)(t0 + r)*64 + cg*4);
        sh4 h; h[0]=(short)f2bf(v[0]); h[1]=(short)f2bf(v[1]); h[2]=(short)f2bf(v[2]); h[3]=(short)f2bf(v[3]);
        int addr = GC_OFF + ((r*128 + cg*8) ^ ((r & 7) << 4));
        *(sh4*)(smem + addr) = h;
    }
    __syncthreads();

    // ---- stage 1: y[64 rows, wave's 32 h-cols + 32 s-cols], K=544 ----
    const int j0 = wave << 5;          // 0,32,64,96: h col base (s cols = 128+j0)
    const int lr = lane & 15, kq = lane >> 4;
    float bh[2], bs[2];
    #pragma unroll
    for (int p = 0; p < 2; ++p) {
        bh[p] = conv_bias[j0 + p*16 + lr];
        bs[p] = conv_bias[128 + j0 + p*16 + lr];
    }

    f32x4 acc[4][4];
    #pragma unroll
    for (int rb = 0; rb < 4; ++rb)
        #pragma unroll
        for (int nt = 0; nt < 4; ++nt) acc[rb][nt] = (f32x4){0.f,0.f,0.f,0.f};

    const sh8* w1v = (const sh8*)w1f;
    #pragma unroll
    for (int ks = 0; ks < 17; ++ks) {
        sh8 bfr[4];
        #pragma unroll
        for (int nt = 0; nt < 4; ++nt) {
            int ntg = (nt < 2) ? ((j0 >> 4) + nt) : (8 + (j0 >> 4) + nt - 2);
            bfr[nt] = w1v[(ks*16 + ntg)*64 + lane];
        }
        sh8 afr[4];
        #pragma unroll
        for (int rb = 0; rb < 4; ++rb) {
            int addr;
            if (ks < 12) {
                int rx = rb*16 + lr + (ks >> 2)*8;
                addr = X_OFF + ((rx*256 + ((ks & 3)*32 + kq*8)*2) ^ ((rx & 7) << 4));
            } else if (ks < 15) {
                int r = rb*16 + lr;
                addr = LC_OFF + ((r*256 + ((ks - 12)*32 + kq*8)*2) ^ ((r & 7) << 4));
            } else {
                int r = rb*16 + lr;
                addr = GC_OFF + ((r*128 + ((ks - 15)*32 + kq*8)*2) ^ ((r & 7) << 4));
            }
            afr[rb] = *(const sh8*)(smem + addr);
        }
        #pragma unroll
        for (int rb = 0; rb < 4; ++rb)
            #pragma unroll
            for (int nt = 0; nt < 4; ++nt)
                acc[rb][nt] = __builtin_amdgcn_mfma_f32_16x16x32_bf16(afr[rb], bfr[nt], acc[rb][nt], 0, 0, 0);
    }

    // all waves must finish reading X before gated overwrites it (G aliases X)
    __syncthreads();

    // ---- gate: tanh(h)*sigmoid(s), write gated to LDS (bf16, swizzled) ----
    #pragma unroll
    for (int rb = 0; rb < 4; ++rb) {
        #pragma unroll
        for (int p = 0; p < 2; ++p) {
            #pragma unroll
            for (int e = 0; e < 4; ++e) {
                float hv = acc[rb][p][e]     + bh[p];
                float sv = acc[rb][p + 2][e] + bs[p];
                float eh = __expf(2.f * hv);
                float th = 1.f - 2.f / (eh + 1.f);
                float sg = 1.f / (1.f + __expf(-sv));
                float g  = th * sg;
                int row = rb*16 + kq*4 + e;
                int col = j0 + p*16 + lr;
                int addr = G_OFF + ((row*256 + col*2) ^ ((row & 7) << 4));
                *(unsigned short*)(smem + addr) = f2bf(g);
            }
        }
    }
    __syncthreads();

    // ---- stage 2: waves 0/1 -> skip[.,0:64]/[.,64:128]; waves 2/3 -> out ----
    const unsigned short* wf = (wave < 2) ? wsf : wof;
    const sh8* wv = (const sh8*)wf;
    const int col0 = (wave & 1) * 64;

    f32x4 a2[4][4];
    #pragma unroll
    for (int rb = 0; rb < 4; ++rb)
        #pragma unroll
        for (int nt = 0; nt < 4; ++nt) a2[rb][nt] = (f32x4){0.f,0.f,0.f,0.f};

    #pragma unroll
    for (int ks = 0; ks < 4; ++ks) {
        sh8 bfr[4];
        #pragma unroll
        for (int nt = 0; nt < 4; ++nt)
            bfr[nt] = wv[(ks*8 + (col0 >> 4) + nt)*64 + lane];
        sh8 afr[4];
        #pragma unroll
        for (int rb = 0; rb < 4; ++rb) {
            int r = rb*16 + lr;
            int addr = G_OFF + ((r*256 + (ks*32 + kq*8)*2) ^ ((r & 7) << 4));
            afr[rb] = *(const sh8*)(smem + addr);
        }
        #pragma unroll
        for (int rb = 0; rb < 4; ++rb)
            #pragma unroll
            for (int nt = 0; nt < 4; ++nt)
                a2[rb][nt] = __builtin_amdgcn_mfma_f32_16x16x32_bf16(afr[rb], bfr[nt], a2[rb][nt], 0, 0, 0);
    }

    // ---- epilogue ----
    float bia[4];
    const float* bvec = (wave < 2) ? skip_bias : out_bias;
    #pragma unroll
    for (int nt = 0; nt < 4; ++nt) bia[nt] = bvec[col0 + nt*16 + lr];

    const size_t obase = (size_t)b * T_LEN * 128;
    if (wave < 2) {
        float* o = out + OUT_HALF + obase;   // skip is output 1
        #pragma unroll
        for (int rb = 0; rb < 4; ++rb)
            #pragma unroll
            for (int nt = 0; nt < 4; ++nt)
                #pragma unroll
                for (int e = 0; e < 4; ++e) {
                    int t = t0 + rb*16 + kq*4 + e;
                    int c = col0 + nt*16 + lr;
                    o[(size_t)t*128 + c] = a2[rb][nt][e] + bia[nt];
                }
    } else {
        float* o = out + obase;              // out is output 0
        const float* xr = xb;
        #pragma unroll
        for (int rb = 0; rb < 4; ++rb)
            #pragma unroll
            for (int nt = 0; nt < 4; ++nt)
                #pragma unroll
                for (int e = 0; e < 4; ++e) {
                    int t = t0 + rb*16 + kq*4 + e;
                    int c = col0 + nt*16 + lr;
                    size_t off = (size_t)t*128 + c;
                    o[off] = (a2[rb][nt][e] + bia[nt] + xr[off]) * 0.70710678118654752f;
                }
    }
}

// ------------------------------ launch -------------------------------------
extern "C" void kernel_launch(void* const* d_in, const int* in_sizes, int n_in,
                              void* d_out, int out_size, void* d_ws, size_t ws_size,
                              hipStream_t stream) {
    const float* x         = (const float*)d_in[0];
    const float* lc        = (const float*)d_in[1];
    const float* gc        = (const float*)d_in[2];
    const float* conv_k    = (const float*)d_in[3];
    const float* conv_g    = (const float*)d_in[4];
    const float* conv_bias = (const float*)d_in[5];
    const float* lc_k      = (const float*)d_in[6];
    const float* lc_g      = (const float*)d_in[7];
    const float* gc_k      = (const float*)d_in[8];
    const float* gc_g      = (const float*)d_in[9];
    const float* skip_k    = (const float*)d_in[10];
    const float* skip_g    = (const float*)d_in[11];
    const float* skip_bias = (const float*)d_in[12];
    const float* out_k     = (const float*)d_in[13];
    const float* out_g     = (const float*)d_in[14];
    const float* out_bias  = (const float*)d_in[15];
    float* out = (float*)d_out;

    float* scales        = (float*)d_ws;
    unsigned short* w1f  = (unsigned short*)((char*)d_ws + 4096);
    unsigned short* wsf  = (unsigned short*)((char*)d_ws + 4096 + 278528);
    unsigned short* wof  = (unsigned short*)((char*)d_ws + 4096 + 278528 + 32768);

    wp_scales<<<5, 256, 0, stream>>>(conv_k, conv_g, lc_k, lc_g, gc_k, gc_g,
                                     skip_k, skip_g, out_k, out_g, scales);
    wp_frags<<<672, 256, 0, stream>>>(conv_k, lc_k, gc_k, skip_k, out_k, scales,
                                      w1f, wsf, wof);
    wn_main<<<2048, 256, 0, stream>>>(x, lc, gc, conv_bias, skip_bias, out_bias,
                                      w1f, wsf, wof, out);
}

// Round 4
// 315.840 us; speedup vs baseline: 1.4503x; 1.4503x over previous
//
#include <hip/hip_runtime.h>
#include <hip/hip_bf16.h>
#include <stddef.h>

// ---------------------------------------------------------------------------
// WaveNet residual block, fused.  B=8 T=16384 C=128 F=256 K=3 dil=8
// K-dim layout for GEMM1 (total 544 = 17 * 32):
//   [0,384)   conv: kk = k*128 + c   -> x[t-16+8k][c]
//   [384,480) lc (80 data + 16 zero pad)
//   [480,544) gc (64)
// Weights stored WN-normalized, bf16, MFMA-fragment order:
//   frag[kstep][ntile][lane][8], value = W[kstep*32 + (lane>>4)*8 + j][ntile*16 + (lane&15)]
// ---------------------------------------------------------------------------

typedef __attribute__((ext_vector_type(4))) float  f32x4;
typedef __attribute__((ext_vector_type(8))) short  sh8;
typedef __attribute__((ext_vector_type(4))) short  sh4;

#define T_LEN   16384
#define OUT_HALF 16777216   // 8*16384*128

static __device__ __forceinline__ unsigned short f2bf(float f) {
    unsigned u = __builtin_bit_cast(unsigned, f);
    unsigned r = u + 0x7FFFu + ((u >> 16) & 1u);
    return (unsigned short)(r >> 16);
}

// ------------------------------ weight prep --------------------------------
// One wave per output channel: 1024 waves total.
//   w in [0,256)    conv  K=384 stride=256
//   w in [256,512)  lc    K=80  stride=256
//   w in [512,768)  gc    K=64  stride=256
//   w in [768,896)  skip  K=128 stride=128
//   w in [896,1024) out   K=128 stride=128
__global__ __launch_bounds__(256)
void wp_scales(const float* __restrict__ conv_k, const float* __restrict__ conv_g,
               const float* __restrict__ lc_k,   const float* __restrict__ lc_g,
               const float* __restrict__ gc_k,   const float* __restrict__ gc_g,
               const float* __restrict__ skip_k, const float* __restrict__ skip_g,
               const float* __restrict__ out_k,  const float* __restrict__ out_g,
               float* __restrict__ scales) {
    int w    = blockIdx.x * 4 + (threadIdx.x >> 6);
    int lane = threadIdx.x & 63;
    const float* W; const float* g; int K, stride, f, sbase;
    if      (w < 256) { W = conv_k; g = conv_g; K = 384; stride = 256; f = w;       sbase = 0;   }
    else if (w < 512) { W = lc_k;   g = lc_g;   K = 80;  stride = 256; f = w - 256; sbase = 256; }
    else if (w < 768) { W = gc_k;   g = gc_g;   K = 64;  stride = 256; f = w - 512; sbase = 512; }
    else if (w < 896) { W = skip_k; g = skip_g; K = 128; stride = 128; f = w - 768; sbase = 768; }
    else              { W = out_k;  g = out_g;  K = 128; stride = 128; f = w - 896; sbase = 896; }
    float ss = 0.f;
    for (int i = lane; i < K; i += 64) { float v = W[i * stride + f]; ss += v * v; }
    #pragma unroll
    for (int off = 32; off; off >>= 1) ss += __shfl_xor(ss, off);
    if (lane == 0) scales[sbase + f] = g[f] * rsqrtf(fmaxf(ss, 1e-12f));
}

__global__ void wp_frags(const float* __restrict__ conv_k, const float* __restrict__ lc_k,
                         const float* __restrict__ gc_k,   const float* __restrict__ skip_k,
                         const float* __restrict__ out_k,  const float* __restrict__ scales,
                         unsigned short* __restrict__ w1f,
                         unsigned short* __restrict__ wsf,
                         unsigned short* __restrict__ wof) {
    int idx = blockIdx.x * 256 + threadIdx.x;
    if (idx < 139264) {                       // W1: [17][16][64][8]
        int j = idx & 7, lane = (idx >> 3) & 63, ntile = (idx >> 9) & 15, ks = idx >> 13;
        int kk = ks*32 + (lane >> 4)*8 + j;
        int f  = ntile*16 + (lane & 15);
        float v;
        if      (kk < 384) v = conv_k[kk*256 + f]        * scales[f];
        else if (kk < 464) v = lc_k[(kk-384)*256 + f]    * scales[256 + f];
        else if (kk < 480) v = 0.f;
        else               v = gc_k[(kk-480)*256 + f]    * scales[512 + f];
        w1f[idx] = f2bf(v);
    } else if (idx < 155648) {                // Wskip: [4][8][64][8]
        int e = idx - 139264;
        int j = e & 7, lane = (e >> 3) & 63, ntile = (e >> 9) & 7, ks = e >> 12;
        int kk = ks*32 + (lane >> 4)*8 + j;
        int s  = ntile*16 + (lane & 15);
        wsf[e] = f2bf(skip_k[kk*128 + s] * scales[768 + s]);
    } else if (idx < 172032) {                // Wout: [4][8][64][8]
        int e = idx - 155648;
        int j = e & 7, lane = (e >> 3) & 63, ntile = (e >> 9) & 7, ks = e >> 12;
        int kk = ks*32 + (lane >> 4)*8 + j;
        int c  = ntile*16 + (lane & 15);
        wof[e] = f2bf(out_k[kk*128 + c] * scales[896 + c]);
    }
}

// ------------------------------ main kernel --------------------------------
// LDS layout (bytes), all XOR-swizzled with ((row&7)<<4); every region has a
// row stride that is a multiple of 128 B, so the XOR is bijective within a row.
//   X_OFF : x tile  [80][128] bf16, row stride 256 B   (rows t0-16 .. t0+63)
//   LC_OFF: lc tile [64][128] bf16, row stride 256 B   (cols 80..127 zero)
//   GC_OFF: gc tile [64][64]  bf16, row stride 128 B
//   G_OFF : gated   [64][128] bf16, row stride 256 B -- ALIASES X (after barrier)
#define X_OFF  0
#define G_OFF  0
#define LC_OFF 20480
#define GC_OFF 36864
#define SMEM_SZ 45056

__global__ __launch_bounds__(256, 3)
void wn_main(const float* __restrict__ x, const float* __restrict__ lc,
             const float* __restrict__ gc,
             const float* __restrict__ conv_bias, const float* __restrict__ skip_bias,
             const float* __restrict__ out_bias,
             const unsigned short* __restrict__ w1f,
             const unsigned short* __restrict__ wsf,
             const unsigned short* __restrict__ wof,
             float* __restrict__ out) {
    __shared__ __align__(16) char smem[SMEM_SZ];

    const int tid  = threadIdx.x;
    const int wave = tid >> 6, lane = tid & 63;
    const int bid  = blockIdx.x;
    const int b    = bid >> 8;          // 256 blocks per batch (T/64)
    const int t0   = (bid & 255) << 6;  // 64 timesteps per block

    const float* xb  = x  + (size_t)b * T_LEN * 128;
    const float* lcb = lc + (size_t)b * T_LEN * 80;
    const float* gcb = gc + (size_t)b * T_LEN * 64;

    // ---- stage x tile: 80 rows x 128 ch = 2560 float4, 10 iters ----
    #pragma unroll
    for (int it = 0; it < 10; ++it) {
        int idx = it*256 + tid;
        int r = idx >> 5, cg = idx & 31;
        int t = t0 - 16 + r;
        f32x4 v = {0.f, 0.f, 0.f, 0.f};
        if (t >= 0) v = *(const f32x4*)(xb + (size_t)t*128 + cg*4);
        sh4 h; h[0]=(short)f2bf(v[0]); h[1]=(short)f2bf(v[1]); h[2]=(short)f2bf(v[2]); h[3]=(short)f2bf(v[3]);
        int addr = X_OFF + ((r*256 + cg*8) ^ ((r & 7) << 4));
        *(sh4*)(smem + addr) = h;
    }
    // ---- stage lc tile: 64 rows x 80 ch = 1280 float4, 5 iters ----
    #pragma unroll
    for (int it = 0; it < 5; ++it) {
        int idx = it*256 + tid;
        int r = idx / 20, cg = idx - r*20;
        f32x4 v = *(const f32x4*)(lcb + (size_t)(t0 + r)*80 + cg*4);
        sh4 h; h[0]=(short)f2bf(v[0]); h[1]=(short)f2bf(v[1]); h[2]=(short)f2bf(v[2]); h[3]=(short)f2bf(v[3]);
        int addr = LC_OFF + ((r*256 + cg*8) ^ ((r & 7) << 4));
        *(sh4*)(smem + addr) = h;
    }
    // lc zero pad cols 80..127: 64 rows x 12 groups of 8B = 768
    #pragma unroll
    for (int it = 0; it < 3; ++it) {
        int idx = it*256 + tid;
        int r = idx / 12, cg2 = idx - r*12;
        sh4 z = {0,0,0,0};
        int addr = LC_OFF + ((r*256 + 160 + cg2*8) ^ ((r & 7) << 4));
        *(sh4*)(smem + addr) = z;
    }
    // ---- stage gc tile: 64 rows x 64 ch = 1024 float4, 4 iters ----
    #pragma unroll
    for (int it = 0; it < 4; ++it) {
        int idx = it*256 + tid;
        int r = idx >> 4, cg = idx & 15;
        f32x4 v = *(const f32x4*)(gcb + (size_t)(t0 + r)*64 + cg*4);
        sh4 h; h[0]=(short)f2bf(v[0]); h[1]=(short)f2bf(v[1]); h[2]=(short)f2bf(v[2]); h[3]=(short)f2bf(v[3]);
        int addr = GC_OFF + ((r*128 + cg*8) ^ ((r & 7) << 4));
        *(sh4*)(smem + addr) = h;
    }
    __syncthreads();

    // ---- stage 1: y[64 rows, wave's 32 h-cols + 32 s-cols], K=544 ----
    const int j0 = wave << 5;          // 0,32,64,96: h col base (s cols = 128+j0)
    const int lr = lane & 15, kq = lane >> 4;
    float bh[2], bs[2];
    #pragma unroll
    for (int p = 0; p < 2; ++p) {
        bh[p] = conv_bias[j0 + p*16 + lr];
        bs[p] = conv_bias[128 + j0 + p*16 + lr];
    }

    f32x4 acc[4][4];
    #pragma unroll
    for (int rb = 0; rb < 4; ++rb)
        #pragma unroll
        for (int nt = 0; nt < 4; ++nt) acc[rb][nt] = (f32x4){0.f,0.f,0.f,0.f};

    const sh8* w1v = (const sh8*)w1f;
    #pragma unroll
    for (int ks = 0; ks < 17; ++ks) {
        sh8 bfr[4];
        #pragma unroll
        for (int nt = 0; nt < 4; ++nt) {
            int ntg = (nt < 2) ? ((j0 >> 4) + nt) : (8 + (j0 >> 4) + nt - 2);
            bfr[nt] = w1v[(ks*16 + ntg)*64 + lane];
        }
        sh8 afr[4];
        #pragma unroll
        for (int rb = 0; rb < 4; ++rb) {
            int addr;
            if (ks < 12) {
                int rx = rb*16 + lr + (ks >> 2)*8;
                addr = X_OFF + ((rx*256 + ((ks & 3)*32 + kq*8)*2) ^ ((rx & 7) << 4));
            } else if (ks < 15) {
                int r = rb*16 + lr;
                addr = LC_OFF + ((r*256 + ((ks - 12)*32 + kq*8)*2) ^ ((r & 7) << 4));
            } else {
                int r = rb*16 + lr;
                addr = GC_OFF + ((r*128 + ((ks - 15)*32 + kq*8)*2) ^ ((r & 7) << 4));
            }
            afr[rb] = *(const sh8*)(smem + addr);
        }
        #pragma unroll
        for (int rb = 0; rb < 4; ++rb)
            #pragma unroll
            for (int nt = 0; nt < 4; ++nt)
                acc[rb][nt] = __builtin_amdgcn_mfma_f32_16x16x32_bf16(afr[rb], bfr[nt], acc[rb][nt], 0, 0, 0);
    }

    // all waves must finish reading X before gated overwrites it (G aliases X)
    __syncthreads();

    // ---- gate: tanh(h)*sigmoid(s), write gated to LDS (bf16, swizzled) ----
    #pragma unroll
    for (int rb = 0; rb < 4; ++rb) {
        #pragma unroll
        for (int p = 0; p < 2; ++p) {
            #pragma unroll
            for (int e = 0; e < 4; ++e) {
                float hv = acc[rb][p][e]     + bh[p];
                float sv = acc[rb][p + 2][e] + bs[p];
                float eh = __expf(2.f * hv);
                float th = 1.f - 2.f / (eh + 1.f);
                float sg = 1.f / (1.f + __expf(-sv));
                float g  = th * sg;
                int row = rb*16 + kq*4 + e;
                int col = j0 + p*16 + lr;
                int addr = G_OFF + ((row*256 + col*2) ^ ((row & 7) << 4));
                *(unsigned short*)(smem + addr) = f2bf(g);
            }
        }
    }
    __syncthreads();

    // ---- stage 2: waves 0/1 -> skip[.,0:64]/[.,64:128]; waves 2/3 -> out ----
    const unsigned short* wf = (wave < 2) ? wsf : wof;
    const sh8* wv = (const sh8*)wf;
    const int col0 = (wave & 1) * 64;

    f32x4 a2[4][4];
    #pragma unroll
    for (int rb = 0; rb < 4; ++rb)
        #pragma unroll
        for (int nt = 0; nt < 4; ++nt) a2[rb][nt] = (f32x4){0.f,0.f,0.f,0.f};

    #pragma unroll
    for (int ks = 0; ks < 4; ++ks) {
        sh8 bfr[4];
        #pragma unroll
        for (int nt = 0; nt < 4; ++nt)
            bfr[nt] = wv[(ks*8 + (col0 >> 4) + nt)*64 + lane];
        sh8 afr[4];
        #pragma unroll
        for (int rb = 0; rb < 4; ++rb) {
            int r = rb*16 + lr;
            int addr = G_OFF + ((r*256 + (ks*32 + kq*8)*2) ^ ((r & 7) << 4));
            afr[rb] = *(const sh8*)(smem + addr);
        }
        #pragma unroll
        for (int rb = 0; rb < 4; ++rb)
            #pragma unroll
            for (int nt = 0; nt < 4; ++nt)
                a2[rb][nt] = __builtin_amdgcn_mfma_f32_16x16x32_bf16(afr[rb], bfr[nt], a2[rb][nt], 0, 0, 0);
    }

    // ---- epilogue ----
    float bia[4];
    const float* bvec = (wave < 2) ? skip_bias : out_bias;
    #pragma unroll
    for (int nt = 0; nt < 4; ++nt) bia[nt] = bvec[col0 + nt*16 + lr];

    const size_t obase = (size_t)b * T_LEN * 128;
    if (wave < 2) {
        float* o = out + OUT_HALF + obase;   // skip is output 1
        #pragma unroll
        for (int rb = 0; rb < 4; ++rb)
            #pragma unroll
            for (int nt = 0; nt < 4; ++nt)
                #pragma unroll
                for (int e = 0; e < 4; ++e) {
                    int t = t0 + rb*16 + kq*4 + e;
                    int c = col0 + nt*16 + lr;
                    o[(size_t)t*128 + c] = a2[rb][nt][e] + bia[nt];
                }
    } else {
        float* o = out + obase;              // out is output 0
        const float* xr = xb;
        #pragma unroll
        for (int rb = 0; rb < 4; ++rb)
            #pragma unroll
            for (int nt = 0; nt < 4; ++nt)
                #pragma unroll
                for (int e = 0; e < 4; ++e) {
                    int t = t0 + rb*16 + kq*4 + e;
                    int c = col0 + nt*16 + lr;
                    size_t off = (size_t)t*128 + c;
                    o[off] = (a2[rb][nt][e] + bia[nt] + xr[off]) * 0.70710678118654752f;
                }
    }
}

// ------------------------------ launch -------------------------------------
extern "C" void kernel_launch(void* const* d_in, const int* in_sizes, int n_in,
                              void* d_out, int out_size, void* d_ws, size_t ws_size,
                              hipStream_t stream) {
    const float* x         = (const float*)d_in[0];
    const float* lc        = (const float*)d_in[1];
    const float* gc        = (const float*)d_in[2];
    const float* conv_k    = (const float*)d_in[3];
    const float* conv_g    = (const float*)d_in[4];
    const float* conv_bias = (const float*)d_in[5];
    const float* lc_k      = (const float*)d_in[6];
    const float* lc_g      = (const float*)d_in[7];
    const float* gc_k      = (const float*)d_in[8];
    const float* gc_g      = (const float*)d_in[9];
    const float* skip_k    = (const float*)d_in[10];
    const float* skip_g    = (const float*)d_in[11];
    const float* skip_bias = (const float*)d_in[12];
    const float* out_k     = (const float*)d_in[13];
    const float* out_g     = (const float*)d_in[14];
    const float* out_bias  = (const float*)d_in[15];
    float* out = (float*)d_out;

    float* scales        = (float*)d_ws;
    unsigned short* w1f  = (unsigned short*)((char*)d_ws + 4096);
    unsigned short* wsf  = (unsigned short*)((char*)d_ws + 4096 + 278528);
    unsigned short* wof  = (unsigned short*)((char*)d_ws + 4096 + 278528 + 32768);

    wp_scales<<<256, 256, 0, stream>>>(conv_k, conv_g, lc_k, lc_g, gc_k, gc_g,
                                       skip_k, skip_g, out_k, out_g, scales);
    wp_frags<<<672, 256, 0, stream>>>(conv_k, lc_k, gc_k, skip_k, out_k, scales,
                                      w1f, wsf, wof);
    wn_main<<<2048, 256, 0, stream>>>(x, lc, gc, conv_bias, skip_bias, out_bias,
                                      w1f, wsf, wof, out);
}